// Round 5
// baseline (280.689 us; speedup 1.0000x reference)
//
#include <hip/hip_runtime.h>
#include <hip/hip_cooperative_groups.h>
#include <math.h>

namespace cg = cooperative_groups;

#define HW   3136   // 56*56
#define NC   512    // channels
#define NB   32     // batch
#define KSEL 256    // top-k
#define NBLK 1024   // 4 blocks/CU * 256 CUs
#define NTHR 256    // 4 waves/block -> 16 waves/CU

typedef float f32x4 __attribute__((ext_vector_type(4)));

// ---------------------------------------------------------------------------
// Fused cooperative kernel: reduce -> sync -> topk -> sync -> gather.
// 1024 blocks x 256 threads (4 blocks/CU, 16 waves/CU for latency hiding).
// ---------------------------------------------------------------------------
__global__ __launch_bounds__(NTHR, 4) void fused_attention(
    const float* __restrict__ x, const float* __restrict__ w,
    float* __restrict__ out, float* __restrict__ desc,
    int* __restrict__ sidx, float* __restrict__ sval)
{
    cg::grid_group grid = cg::this_grid();
    const int tid  = threadIdx.x;
    const int wid  = tid >> 6;     // 0..3
    const int lane = tid & 63;

    // ---- Phase 1: per-(b,c) mean+max over HW; desc = mean + max ----
    // conv(avg)+conv(mx) == conv(avg+mx) by linearity (no bias).
    {
        const int row0 = blockIdx.x * 16 + wid * 4;   // 1024 blocks * 16 rows
#pragma unroll
        for (int r = 0; r < 4; ++r) {
            const int row = row0 + r;
            const f32x4* p = (const f32x4*)(x + (size_t)row * HW);
            float s = 0.0f, m = -INFINITY;
#pragma unroll
            for (int i = 0; i < 12; ++i) {            // 12*64 = 768 float4
                f32x4 v = p[lane + i * 64];
                s += (v.x + v.y) + (v.z + v.w);
                m = fmaxf(m, fmaxf(fmaxf(v.x, v.y), fmaxf(v.z, v.w)));
            }
            if (lane < 16) {                          // tail: 784-768
                f32x4 v = p[lane + 768];
                s += (v.x + v.y) + (v.z + v.w);
                m = fmaxf(m, fmaxf(fmaxf(v.x, v.y), fmaxf(v.z, v.w)));
            }
#pragma unroll
            for (int off = 32; off; off >>= 1) {
                s += __shfl_down(s, off, 64);
                m = fmaxf(m, __shfl_down(m, off, 64));
            }
            if (lane == 0) desc[row] = s * (1.0f / (float)HW) + m;
        }
    }

    grid.sync();

    // ---- Phase 2: blocks 0..31 -> conv1d + sigmoid + top-K select ----
    // 256 threads/block: thread t owns channels c0=t and c1=t+256.
    __shared__ float s_d[NC + 2];
    __shared__ float s_score[NC];
    __shared__ int   s_wcnt[8];
    if (blockIdx.x < NB) {
        const int b = blockIdx.x;
        if (tid == 0) { s_d[0] = 0.0f; s_d[NC + 1] = 0.0f; }
        s_d[tid + 1]   = desc[b * NC + tid];
        s_d[tid + 257] = desc[b * NC + tid + 256];
        __syncthreads();

        const float w0 = w[0], w1 = w[1], w2 = w[2];
        // cross-correlation (lax conv does NOT flip the kernel)
        const int c0 = tid, c1 = tid + 256;
        const float t0 = s_d[c0] * w0 + s_d[c0 + 1] * w1 + s_d[c0 + 2] * w2;
        const float t1 = s_d[c1] * w0 + s_d[c1 + 1] * w1 + s_d[c1 + 2] * w2;
        const float sc0 = 1.0f / (1.0f + expf(-t0));
        const float sc1 = 1.0f / (1.0f + expf(-t1));
        s_score[c0] = sc0;
        s_score[c1] = sc1;
        __syncthreads();

        int rank0 = 0, rank1 = 0;
        for (int j = 0; j < NC; ++j) {
            const float sj = s_score[j];
            rank0 += (sj > sc0) || (sj == sc0 && j < c0);   // lax.top_k tie-break
            rank1 += (sj > sc1) || (sj == sc1 && j < c1);
        }
        const int flag0 = (rank0 < KSEL) ? 1 : 0;
        const int flag1 = (rank1 < KSEL) ? 1 : 0;

        // chunk i covers channels [64i, 64i+64): chunks 0..3 from flag0
        // ballots (waves 0..3), chunks 4..7 from flag1 ballots.
        const unsigned long long bal0 = __ballot(flag0);
        const unsigned long long bal1 = __ballot(flag1);
        if (lane == 0) {
            s_wcnt[wid]     = __popcll(bal0);
            s_wcnt[wid + 4] = __popcll(bal1);
        }
        __syncthreads();

        const unsigned long long lmask = (1ULL << lane) - 1ULL;
        if (flag0) {   // ascending-channel compaction == reference argsort re-sort
            int pos = __popcll(bal0 & lmask);
            for (int j = 0; j < wid; ++j) pos += s_wcnt[j];
            sidx[b * KSEL + pos] = c0;
            sval[b * KSEL + pos] = sc0;
        }
        if (flag1) {
            int pos = __popcll(bal1 & lmask);
            for (int j = 0; j < wid + 4; ++j) pos += s_wcnt[j];
            sidx[b * KSEL + pos] = c1;
            sval[b * KSEL + pos] = sc1;
        }
    }

    grid.sync();

    // ---- Phase 3: gather selected channels, scale, NT-store ----
    {
        const int t = tid;
        for (int p = 0; p < 8; ++p) {              // 1024 blocks * 8 = 8192 pairs
            const int bk = blockIdx.x * 8 + p;
            const int b  = bk >> 8;                // KSEL == 256
            const int ch = sidx[bk];
            const float sv = sval[bk];

            const f32x4* src = (const f32x4*)(x + ((size_t)b * NC + ch) * HW);
            f32x4*       dst = (f32x4*)(out + (size_t)bk * HW);

#pragma unroll
            for (int i = 0; i < 3; ++i) {          // 784 = 3*256 + 16
                f32x4 v = src[t + i * 256];
                v.x *= sv; v.y *= sv; v.z *= sv; v.w *= sv;
                __builtin_nontemporal_store(v, &dst[t + i * 256]);
            }
            if (t < 16) {
                f32x4 v = src[t + 768];
                v.x *= sv; v.y *= sv; v.z *= sv; v.w *= sv;
                __builtin_nontemporal_store(v, &dst[t + 768]);
            }
        }
    }
}

// ---------------------------------------------------------------------------
// Fallback path (proven round-2 kernels) if cooperative launch is rejected.
// ---------------------------------------------------------------------------
__global__ __launch_bounds__(256) void reduce_mean_max(
    const float* __restrict__ x, float* __restrict__ desc)
{
    const int gwave = (blockIdx.x * blockDim.x + threadIdx.x) >> 6;
    const int lane  = threadIdx.x & 63;
    const f32x4* p = (const f32x4*)(x + (size_t)gwave * HW);
    float s = 0.0f, m = -INFINITY;
#pragma unroll
    for (int i = 0; i < 12; ++i) {
        f32x4 v = p[lane + i * 64];
        s += (v.x + v.y) + (v.z + v.w);
        m = fmaxf(m, fmaxf(fmaxf(v.x, v.y), fmaxf(v.z, v.w)));
    }
    if (lane < 16) {
        f32x4 v = p[lane + 768];
        s += (v.x + v.y) + (v.z + v.w);
        m = fmaxf(m, fmaxf(fmaxf(v.x, v.y), fmaxf(v.z, v.w)));
    }
#pragma unroll
    for (int off = 32; off; off >>= 1) {
        s += __shfl_down(s, off, 64);
        m = fmaxf(m, __shfl_down(m, off, 64));
    }
    if (lane == 0) desc[gwave] = s * (1.0f / (float)HW) + m;
}

__global__ __launch_bounds__(512) void score_topk(
    const float* __restrict__ desc, const float* __restrict__ w,
    int* __restrict__ sidx, float* __restrict__ sval)
{
    const int b = blockIdx.x;
    const int c = threadIdx.x;
    __shared__ float s_d[NC + 2];
    __shared__ float s_score[NC];
    __shared__ int   s_wcnt[8];
    if (c == 0) { s_d[0] = 0.0f; s_d[NC + 1] = 0.0f; }
    s_d[c + 1] = desc[b * NC + c];
    __syncthreads();
    const float w0 = w[0], w1 = w[1], w2 = w[2];
    const float t = s_d[c] * w0 + s_d[c + 1] * w1 + s_d[c + 2] * w2;
    const float score = 1.0f / (1.0f + expf(-t));
    s_score[c] = score;
    __syncthreads();
    int rank = 0;
    for (int j = 0; j < NC; ++j) {
        const float sj = s_score[j];
        rank += (sj > score) || (sj == score && j < c);
    }
    const int flag = (rank < KSEL) ? 1 : 0;
    const unsigned long long bal = __ballot(flag);
    const int wid = c >> 6, lane = c & 63;
    if (lane == 0) s_wcnt[wid] = __popcll(bal);
    __syncthreads();
    if (flag) {
        int pos = __popcll(bal & ((1ULL << lane) - 1ULL));
        for (int wj = 0; wj < wid; ++wj) pos += s_wcnt[wj];
        sidx[b * KSEL + pos] = c;
        sval[b * KSEL + pos] = score;
    }
}

__global__ __launch_bounds__(256) void gather_scale(
    const float* __restrict__ x, const int* __restrict__ sidx,
    const float* __restrict__ sval, float* __restrict__ out)
{
    const int bk = blockIdx.x;
    const int b  = bk >> 8;
    const int ch = sidx[bk];
    const float sv = sval[bk];
    const f32x4* src = (const f32x4*)(x + ((size_t)b * NC + ch) * HW);
    f32x4*       dst = (f32x4*)(out + (size_t)bk * HW);
    const int t = threadIdx.x;
#pragma unroll
    for (int i = 0; i < 3; ++i) {
        f32x4 v = src[t + i * 256];
        v.x *= sv; v.y *= sv; v.z *= sv; v.w *= sv;
        __builtin_nontemporal_store(v, &dst[t + i * 256]);
    }
    if (t < 16) {
        f32x4 v = src[t + 768];
        v.x *= sv; v.y *= sv; v.z *= sv; v.w *= sv;
        __builtin_nontemporal_store(v, &dst[t + 768]);
    }
}

extern "C" void kernel_launch(void* const* d_in, const int* in_sizes, int n_in,
                              void* d_out, int out_size, void* d_ws, size_t ws_size,
                              hipStream_t stream)
{
    const float* x = (const float*)d_in[0];   // [32,512,56,56]
    const float* w = (const float*)d_in[1];   // [1,1,3] -> 3 floats
    float* out = (float*)d_out;               // [32,256,56,56]

    // workspace (floats): desc[16384] | sval[8192] | sidx[8192 ints]
    float* desc = (float*)d_ws;
    float* sval = desc + NB * NC;
    int*   sidx = (int*)(sval + NB * KSEL);

    void* args[] = { (void*)&x, (void*)&w, (void*)&out,
                     (void*)&desc, (void*)&sidx, (void*)&sval };
    hipError_t err = hipLaunchCooperativeKernel((const void*)fused_attention,
                                                dim3(NBLK), dim3(NTHR), args, 0, stream);
    if (err != hipSuccess) {
        // deterministic fallback: proven 3-kernel path
        reduce_mean_max<<<(NB * NC) / 4, 256, 0, stream>>>(x, desc);
        score_topk<<<NB, NC, 0, stream>>>(desc, w, sidx, sval);
        gather_scale<<<NB * KSEL, 256, 0, stream>>>(x, sidx, sval, out);
    }
}

// Round 6
// 226.375 us; speedup vs baseline: 1.2399x; 1.2399x over previous
//
#include <hip/hip_runtime.h>
#include <math.h>

#define HW   3136   // 56*56
#define NC   512    // channels
#define NB   32     // batch
#define KSEL 256    // top-k

typedef float f32x4 __attribute__((ext_vector_type(4)));

// ---------------------------------------------------------------------------
// Kernel A: per-(b,c) mean+max reduce; the 128th-finishing block of each batch
// additionally computes that batch's conv1d+sigmoid+top-K inline (no extra
// dispatch, no grid barrier). desc traffic uses agent-scope atomics so the
// consumer block (possibly on another XCD) never sees stale L2 data.
// 4096 blocks x 256 threads; block i reduces rows 4i..4i+3 (one row per wave),
// all rows of a block belong to one batch (512 rows/batch, 128 blocks/batch).
// ---------------------------------------------------------------------------
__global__ __launch_bounds__(256) void reduce_topk(
    const float* __restrict__ x, const float* __restrict__ w,
    float* __restrict__ desc, unsigned int* __restrict__ counters,
    int* __restrict__ sidx, float* __restrict__ sval)
{
    const int tid  = threadIdx.x;
    const int wid  = tid >> 6;      // 0..3
    const int lane = tid & 63;
    const int row0 = blockIdx.x * 4;
    const int b    = row0 >> 9;     // batch (no block spans a batch boundary)

    // ---- reduce: one row per wave; desc = mean + max (conv is linear, no bias)
    {
        const int row = row0 + wid;
        const f32x4* p = (const f32x4*)(x + (size_t)row * HW);
        float s = 0.0f, m = -INFINITY;
#pragma unroll
        for (int i = 0; i < 12; ++i) {          // 12*64 = 768 float4
            f32x4 v = p[lane + i * 64];
            s += (v.x + v.y) + (v.z + v.w);
            m = fmaxf(m, fmaxf(fmaxf(v.x, v.y), fmaxf(v.z, v.w)));
        }
        if (lane < 16) {                        // tail: 784-768
            f32x4 v = p[lane + 768];
            s += (v.x + v.y) + (v.z + v.w);
            m = fmaxf(m, fmaxf(fmaxf(v.x, v.y), fmaxf(v.z, v.w)));
        }
#pragma unroll
        for (int off = 32; off; off >>= 1) {
            s += __shfl_down(s, off, 64);
            m = fmaxf(m, __shfl_down(m, off, 64));
        }
        if (lane == 0) {
            // agent-scope store: coherent past the per-XCD L2
            __hip_atomic_store(&desc[row], s * (1.0f / (float)HW) + m,
                               __ATOMIC_RELAXED, __HIP_MEMORY_SCOPE_AGENT);
        }
    }

    __syncthreads();   // all 4 waves' desc stores happen-before tid0's signal

    __shared__ unsigned int s_old;
    if (tid == 0)
        s_old = __hip_atomic_fetch_add(&counters[b], 1u,
                                       __ATOMIC_ACQ_REL, __HIP_MEMORY_SCOPE_AGENT);
    __syncthreads();
    if (s_old != 127u) return;   // only the last finisher of batch b continues

    // ---- top-K for batch b (validated 256-thread dual-ballot variant) ----
    __shared__ float s_d[NC + 2];
    __shared__ float s_score[NC];
    __shared__ int   s_wcnt[8];

    if (tid == 0) { s_d[0] = 0.0f; s_d[NC + 1] = 0.0f; }
    s_d[tid + 1]   = __hip_atomic_load(&desc[b * NC + tid],
                                       __ATOMIC_RELAXED, __HIP_MEMORY_SCOPE_AGENT);
    s_d[tid + 257] = __hip_atomic_load(&desc[b * NC + tid + 256],
                                       __ATOMIC_RELAXED, __HIP_MEMORY_SCOPE_AGENT);
    __syncthreads();

    const float w0 = w[0], w1 = w[1], w2 = w[2];
    // cross-correlation (lax conv does NOT flip the kernel)
    const int c0 = tid, c1 = tid + 256;
    const float t0 = s_d[c0] * w0 + s_d[c0 + 1] * w1 + s_d[c0 + 2] * w2;
    const float t1 = s_d[c1] * w0 + s_d[c1 + 1] * w1 + s_d[c1 + 2] * w2;
    const float sc0 = 1.0f / (1.0f + expf(-t0));
    const float sc1 = 1.0f / (1.0f + expf(-t1));
    s_score[c0] = sc0;
    s_score[c1] = sc1;
    __syncthreads();

    int rank0 = 0, rank1 = 0;
    for (int j = 0; j < NC; ++j) {
        const float sj = s_score[j];
        rank0 += (sj > sc0) || (sj == sc0 && j < c0);   // lax.top_k tie-break
        rank1 += (sj > sc1) || (sj == sc1 && j < c1);
    }
    const int flag0 = (rank0 < KSEL) ? 1 : 0;
    const int flag1 = (rank1 < KSEL) ? 1 : 0;

    // chunk i covers channels [64i,64i+64): chunks 0..3 from flag0 ballots
    // (waves 0..3), chunks 4..7 from flag1 ballots.
    const unsigned long long bal0 = __ballot(flag0);
    const unsigned long long bal1 = __ballot(flag1);
    if (lane == 0) {
        s_wcnt[wid]     = __popcll(bal0);
        s_wcnt[wid + 4] = __popcll(bal1);
    }
    __syncthreads();

    const unsigned long long lmask = (1ULL << lane) - 1ULL;
    if (flag0) {   // ascending-channel compaction == reference argsort re-sort
        int pos = __popcll(bal0 & lmask);
        for (int j = 0; j < wid; ++j) pos += s_wcnt[j];
        sidx[b * KSEL + pos] = c0;
        sval[b * KSEL + pos] = sc0;
    }
    if (flag1) {
        int pos = __popcll(bal1 & lmask);
        for (int j = 0; j < wid + 4; ++j) pos += s_wcnt[j];
        sidx[b * KSEL + pos] = c1;
        sval[b * KSEL + pos] = sc1;
    }
}

// ---------------------------------------------------------------------------
// Kernel B: gather selected channels, scale, NT-store (proven round-2 code).
// x reads should hit Infinity Cache (fetched by kernel A); NT stores keep
// the output from evicting x.
// ---------------------------------------------------------------------------
__global__ __launch_bounds__(256) void gather_scale(
    const float* __restrict__ x, const int* __restrict__ sidx,
    const float* __restrict__ sval, float* __restrict__ out)
{
    const int bk = blockIdx.x;          // b*KSEL + k
    const int b  = bk >> 8;             // KSEL == 256
    const int ch = sidx[bk];
    const float sv = sval[bk];

    const f32x4* src = (const f32x4*)(x + ((size_t)b * NC + ch) * HW);
    f32x4*       dst = (f32x4*)(out + (size_t)bk * HW);

    const int t = threadIdx.x;
#pragma unroll
    for (int i = 0; i < 3; ++i) {       // 784 = 3*256 + 16
        f32x4 v = src[t + i * 256];
        v.x *= sv; v.y *= sv; v.z *= sv; v.w *= sv;
        __builtin_nontemporal_store(v, &dst[t + i * 256]);
    }
    if (t < 16) {
        f32x4 v = src[t + 768];
        v.x *= sv; v.y *= sv; v.z *= sv; v.w *= sv;
        __builtin_nontemporal_store(v, &dst[t + 768]);
    }
}

extern "C" void kernel_launch(void* const* d_in, const int* in_sizes, int n_in,
                              void* d_out, int out_size, void* d_ws, size_t ws_size,
                              hipStream_t stream)
{
    const float* x = (const float*)d_in[0];   // [32,512,56,56]
    const float* w = (const float*)d_in[1];   // [1,1,3] -> 3 floats
    float* out = (float*)d_out;               // [32,256,56,56]

    // ws layout (floats): desc[16384] | sval[8192] | sidx[8192 i32] | counters[32 u32]
    float* desc = (float*)d_ws;
    float* sval = desc + NB * NC;
    int*   sidx = (int*)(sval + NB * KSEL);
    unsigned int* counters = (unsigned int*)(sidx + NB * KSEL);

    // counters must be zero every call (ws is poisoned, not re-zeroed)
    hipMemsetAsync(counters, 0, NB * sizeof(unsigned int), stream);

    // Kernel A: reduce + inline per-batch topk (last-finisher block)
    reduce_topk<<<(NB * NC) / 4, 256, 0, stream>>>(x, w, desc, counters, sidx, sval);

    // Kernel B: gather
    gather_scale<<<NB * KSEL, 256, 0, stream>>>(x, sidx, sval, out);
}

// Round 7
// 128.901 us; speedup vs baseline: 2.1776x; 1.7562x over previous
//
#include <hip/hip_runtime.h>
#include <math.h>

#define HW   3136   // 56*56
#define NC   512    // channels
#define NB   32     // batch
#define KSEL 256    // top-k

typedef float f32x4 __attribute__((ext_vector_type(4)));

// ---------------------------------------------------------------------------
// Kernel A: per-(b,c) mean+max reduce; the 128th-finishing block of each batch
// computes that batch's conv1d+sigmoid+top-K inline.
//
// Cross-block protocol is ALL RELAXED at agent scope -> zero cache-maintenance
// instructions (round 6's ACQ_REL emitted per-block L2 wb/inv = 305us disaster).
// Ordering by completion: sc1 desc stores are coherence-point visible when
// retired; __syncthreads() drains vmcnt(0) before tid0's fetch_add issues, so
// counter==127 implies all 128 blocks' desc stores are globally visible; the
// finisher re-reads desc with sc1 relaxed loads (bypasses stale L1/L2).
// ---------------------------------------------------------------------------
__global__ __launch_bounds__(256) void reduce_topk(
    const float* __restrict__ x, const float* __restrict__ w,
    float* __restrict__ desc, unsigned int* __restrict__ counters,
    int* __restrict__ sidx, float* __restrict__ sval)
{
    const int tid  = threadIdx.x;
    const int wid  = tid >> 6;      // 0..3
    const int lane = tid & 63;
    const int row0 = blockIdx.x * 4;
    const int b    = row0 >> 9;     // batch (no block spans a batch boundary)

    // ---- reduce: one row per wave; desc = mean + max (conv is linear, no bias)
    {
        const int row = row0 + wid;
        const f32x4* p = (const f32x4*)(x + (size_t)row * HW);
        float s = 0.0f, m = -INFINITY;
#pragma unroll
        for (int i = 0; i < 12; ++i) {          // 12*64 = 768 float4
            f32x4 v = p[lane + i * 64];
            s += (v.x + v.y) + (v.z + v.w);
            m = fmaxf(m, fmaxf(fmaxf(v.x, v.y), fmaxf(v.z, v.w)));
        }
        if (lane < 16) {                        // tail: 784-768
            f32x4 v = p[lane + 768];
            s += (v.x + v.y) + (v.z + v.w);
            m = fmaxf(m, fmaxf(fmaxf(v.x, v.y), fmaxf(v.z, v.w)));
        }
#pragma unroll
        for (int off = 32; off; off >>= 1) {
            s += __shfl_down(s, off, 64);
            m = fmaxf(m, __shfl_down(m, off, 64));
        }
        if (lane == 0) {
            __hip_atomic_store(&desc[row], s * (1.0f / (float)HW) + m,
                               __ATOMIC_RELAXED, __HIP_MEMORY_SCOPE_AGENT);
        }
    }

    __syncthreads();   // drains vmcnt(0): all 4 desc stores complete before signal

    __shared__ unsigned int s_old;
    if (tid == 0)
        s_old = __hip_atomic_fetch_add(&counters[b], 1u,
                                       __ATOMIC_RELAXED, __HIP_MEMORY_SCOPE_AGENT);
    __syncthreads();
    if (s_old != 127u) return;   // only the last finisher of batch b continues

    // ---- top-K for batch b (proven 256-thread dual-ballot variant) ----
    __shared__ float s_d[NC + 2];
    __shared__ float s_score[NC];
    __shared__ int   s_wcnt[8];

    if (tid == 0) { s_d[0] = 0.0f; s_d[NC + 1] = 0.0f; }
    s_d[tid + 1]   = __hip_atomic_load(&desc[b * NC + tid],
                                       __ATOMIC_RELAXED, __HIP_MEMORY_SCOPE_AGENT);
    s_d[tid + 257] = __hip_atomic_load(&desc[b * NC + tid + 256],
                                       __ATOMIC_RELAXED, __HIP_MEMORY_SCOPE_AGENT);
    __syncthreads();

    const float w0 = w[0], w1 = w[1], w2 = w[2];
    // cross-correlation (lax conv does NOT flip the kernel)
    const int c0 = tid, c1 = tid + 256;
    const float t0 = s_d[c0] * w0 + s_d[c0 + 1] * w1 + s_d[c0 + 2] * w2;
    const float t1 = s_d[c1] * w0 + s_d[c1 + 1] * w1 + s_d[c1 + 2] * w2;
    const float sc0 = 1.0f / (1.0f + expf(-t0));
    const float sc1 = 1.0f / (1.0f + expf(-t1));
    s_score[c0] = sc0;
    s_score[c1] = sc1;
    __syncthreads();

    int rank0 = 0, rank1 = 0;
    for (int j = 0; j < NC; ++j) {
        const float sj = s_score[j];
        rank0 += (sj > sc0) || (sj == sc0 && j < c0);   // lax.top_k tie-break
        rank1 += (sj > sc1) || (sj == sc1 && j < c1);
    }
    const int flag0 = (rank0 < KSEL) ? 1 : 0;
    const int flag1 = (rank1 < KSEL) ? 1 : 0;

    // chunk i covers channels [64i,64i+64): chunks 0..3 from flag0 ballots
    // (waves 0..3), chunks 4..7 from flag1 ballots.
    const unsigned long long bal0 = __ballot(flag0);
    const unsigned long long bal1 = __ballot(flag1);
    if (lane == 0) {
        s_wcnt[wid]     = __popcll(bal0);
        s_wcnt[wid + 4] = __popcll(bal1);
    }
    __syncthreads();

    const unsigned long long lmask = (1ULL << lane) - 1ULL;
    if (flag0) {   // ascending-channel compaction == reference argsort re-sort
        int pos = __popcll(bal0 & lmask);
        for (int j = 0; j < wid; ++j) pos += s_wcnt[j];
        sidx[b * KSEL + pos] = c0;
        sval[b * KSEL + pos] = sc0;
    }
    if (flag1) {
        int pos = __popcll(bal1 & lmask);
        for (int j = 0; j < wid + 4; ++j) pos += s_wcnt[j];
        sidx[b * KSEL + pos] = c1;
        sval[b * KSEL + pos] = sc1;
    }
}

// ---------------------------------------------------------------------------
// Kernel B: gather selected channels, scale. NT loads (x re-read is single-use,
// served from Infinity Cache) + NT stores (don't evict x from L3).
// ---------------------------------------------------------------------------
__global__ __launch_bounds__(256) void gather_scale(
    const float* __restrict__ x, const int* __restrict__ sidx,
    const float* __restrict__ sval, float* __restrict__ out)
{
    const int bk = blockIdx.x;          // b*KSEL + k
    const int b  = bk >> 8;             // KSEL == 256
    const int ch = sidx[bk];
    const float sv = sval[bk];

    const f32x4* src = (const f32x4*)(x + ((size_t)b * NC + ch) * HW);
    f32x4*       dst = (f32x4*)(out + (size_t)bk * HW);

    const int t = threadIdx.x;
#pragma unroll
    for (int i = 0; i < 3; ++i) {       // 784 = 3*256 + 16
        f32x4 v = __builtin_nontemporal_load(&src[t + i * 256]);
        v.x *= sv; v.y *= sv; v.z *= sv; v.w *= sv;
        __builtin_nontemporal_store(v, &dst[t + i * 256]);
    }
    if (t < 16) {
        f32x4 v = __builtin_nontemporal_load(&src[t + 768]);
        v.x *= sv; v.y *= sv; v.z *= sv; v.w *= sv;
        __builtin_nontemporal_store(v, &dst[t + 768]);
    }
}

extern "C" void kernel_launch(void* const* d_in, const int* in_sizes, int n_in,
                              void* d_out, int out_size, void* d_ws, size_t ws_size,
                              hipStream_t stream)
{
    const float* x = (const float*)d_in[0];   // [32,512,56,56]
    const float* w = (const float*)d_in[1];   // [1,1,3] -> 3 floats
    float* out = (float*)d_out;               // [32,256,56,56]

    // ws layout (floats): desc[16384] | sval[8192] | sidx[8192 i32] | counters[32 u32]
    float* desc = (float*)d_ws;
    float* sval = desc + NB * NC;
    int*   sidx = (int*)(sval + NB * KSEL);
    unsigned int* counters = (unsigned int*)(sidx + NB * KSEL);

    // counters must be zero every call (ws is poisoned once, never re-zeroed)
    hipMemsetAsync(counters, 0, NB * sizeof(unsigned int), stream);

    // Kernel A: reduce + inline per-batch topk (relaxed last-finisher protocol)
    reduce_topk<<<(NB * NC) / 4, 256, 0, stream>>>(x, w, desc, counters, sidx, sval);

    // Kernel B: gather
    gather_scale<<<NB * KSEL, 256, 0, stream>>>(x, sidx, sval, out);
}

// Round 8
// 81.645 us; speedup vs baseline: 3.4379x; 1.5788x over previous
//
#include <hip/hip_runtime.h>
#include <math.h>

#define HW   3136   // 56*56
#define NC   512    // channels
#define NB   32     // batch
#define KSEL 256    // top-k

typedef float f32x4 __attribute__((ext_vector_type(4)));

// ---------------------------------------------------------------------------
// Kernel 1: per-(b,c) mean+max over HW; desc = mean + max (conv is linear,
// no bias, so conv(avg)+conv(mx) == conv(avg+mx)). One wave per channel row.
// Plain loads so x allocates in L2/L3 -> kernel 3 re-reads hit Infinity Cache.
// ---------------------------------------------------------------------------
__global__ __launch_bounds__(256) void reduce_mean_max(
    const float* __restrict__ x, float* __restrict__ desc)
{
    const int gwave = (blockIdx.x * blockDim.x + threadIdx.x) >> 6; // b*NC + c
    const int lane  = threadIdx.x & 63;

    const f32x4* p = (const f32x4*)(x + (size_t)gwave * HW);
    float s = 0.0f, m = -INFINITY;
#pragma unroll
    for (int i = 0; i < 12; ++i) {          // 12*64 = 768 float4
        f32x4 v = p[lane + i * 64];
        s += (v.x + v.y) + (v.z + v.w);
        m = fmaxf(m, fmaxf(fmaxf(v.x, v.y), fmaxf(v.z, v.w)));
    }
    if (lane < 16) {                        // tail: 784-768
        f32x4 v = p[lane + 768];
        s += (v.x + v.y) + (v.z + v.w);
        m = fmaxf(m, fmaxf(fmaxf(v.x, v.y), fmaxf(v.z, v.w)));
    }
#pragma unroll
    for (int off = 32; off; off >>= 1) {
        s += __shfl_down(s, off, 64);
        m = fmaxf(m, __shfl_down(m, off, 64));
    }
    if (lane == 0) desc[gwave] = s * (1.0f / (float)HW) + m;
}

// ---------------------------------------------------------------------------
// Kernel 2: per-batch conv1d + sigmoid + top-K select (proven 512-thread
// rank/ballot version). Ascending-channel compaction == reference argsort.
// ---------------------------------------------------------------------------
__global__ __launch_bounds__(512) void score_topk(
    const float* __restrict__ desc, const float* __restrict__ w,
    int* __restrict__ sidx, float* __restrict__ sval)
{
    const int b = blockIdx.x;
    const int c = threadIdx.x;
    __shared__ float s_d[NC + 2];
    __shared__ float s_score[NC];
    __shared__ int   s_wcnt[8];

    if (c == 0) { s_d[0] = 0.0f; s_d[NC + 1] = 0.0f; }
    s_d[c + 1] = desc[b * NC + c];
    __syncthreads();

    const float w0 = w[0], w1 = w[1], w2 = w[2];
    // cross-correlation (lax conv does NOT flip the kernel)
    const float t = s_d[c] * w0 + s_d[c + 1] * w1 + s_d[c + 2] * w2;
    const float score = 1.0f / (1.0f + expf(-t));
    s_score[c] = score;
    __syncthreads();

    int rank = 0;
    for (int j = 0; j < NC; ++j) {
        const float sj = s_score[j];
        rank += (sj > score) || (sj == score && j < c);   // lax.top_k tie-break
    }
    const int flag = (rank < KSEL) ? 1 : 0;

    const unsigned long long bal = __ballot(flag);
    const int wid = c >> 6, lane = c & 63;
    if (lane == 0) s_wcnt[wid] = __popcll(bal);
    __syncthreads();

    if (flag) {
        int pos = __popcll(bal & ((1ULL << lane) - 1ULL));
        for (int wj = 0; wj < wid; ++wj) pos += s_wcnt[wj];
        sidx[b * KSEL + pos] = c;
        sval[b * KSEL + pos] = score;
    }
}

// ---------------------------------------------------------------------------
// Kernel 3: gather selected channels, scale. NT loads (single-use re-read,
// served from Infinity Cache) + NT stores (don't evict x from L3).
// ---------------------------------------------------------------------------
__global__ __launch_bounds__(256) void gather_scale(
    const float* __restrict__ x, const int* __restrict__ sidx,
    const float* __restrict__ sval, float* __restrict__ out)
{
    const int bk = blockIdx.x;          // b*KSEL + k
    const int b  = bk >> 8;             // KSEL == 256
    const int ch = sidx[bk];
    const float sv = sval[bk];

    const f32x4* src = (const f32x4*)(x + ((size_t)b * NC + ch) * HW);
    f32x4*       dst = (f32x4*)(out + (size_t)bk * HW);

    const int t = threadIdx.x;
#pragma unroll
    for (int i = 0; i < 3; ++i) {       // 784 = 3*256 + 16
        f32x4 v = __builtin_nontemporal_load(&src[t + i * 256]);
        v.x *= sv; v.y *= sv; v.z *= sv; v.w *= sv;
        __builtin_nontemporal_store(v, &dst[t + i * 256]);
    }
    if (t < 16) {
        f32x4 v = __builtin_nontemporal_load(&src[t + 768]);
        v.x *= sv; v.y *= sv; v.z *= sv; v.w *= sv;
        __builtin_nontemporal_store(v, &dst[t + 768]);
    }
}

extern "C" void kernel_launch(void* const* d_in, const int* in_sizes, int n_in,
                              void* d_out, int out_size, void* d_ws, size_t ws_size,
                              hipStream_t stream)
{
    const float* x = (const float*)d_in[0];   // [32,512,56,56]
    const float* w = (const float*)d_in[1];   // [1,1,3] -> 3 floats
    float* out = (float*)d_out;               // [32,256,56,56]

    // ws layout (floats): desc[16384] | sval[8192] | sidx[8192 i32]
    float* desc = (float*)d_ws;
    float* sval = desc + NB * NC;
    int*   sidx = (int*)(sval + NB * KSEL);

    // Kernel 1: 16384 channel rows, 1 wave each, 4 waves/block -> 4096 blocks
    reduce_mean_max<<<(NB * NC) / 4, 256, 0, stream>>>(x, desc);

    // Kernel 2: one block per batch sample
    score_topk<<<NB, NC, 0, stream>>>(desc, w, sidx, sval);

    // Kernel 3: one block per selected (b,k) channel
    gather_scale<<<NB * KSEL, 256, 0, stream>>>(x, sidx, sval, out);
}